// Round 19
// baseline (125.884 us; speedup 1.0000x reference)
//
#include <hip/hip_runtime.h>
#include <hip/hip_bf16.h>
#include <stdint.h>

// x[2,8192,2048] f32; weight[2048,2048] fp8e4m3fn pushed as f32 values;
// scales pushed as f32 scalars (established rounds 0-18). out[2,8192,2048] f32.
#define M_DIM 16384
#define N_DIM 2048
#define K_DIM 2048

typedef float    f32x4 __attribute__((ext_vector_type(4)));
typedef uint32_t u32x4 __attribute__((ext_vector_type(4)));
typedef int      i32x8 __attribute__((ext_vector_type(8)));

#define SCALE_ONE 0x7F7F7F7F   // e8m0 exp 127 -> 1.0 in all byte lanes

__device__ inline uint32_t quant4(float4 v, float rs) {
    float q0 = fminf(fmaxf(v.x * rs, -448.f), 448.f);
    float q1 = fminf(fmaxf(v.y * rs, -448.f), 448.f);
    float q2 = fminf(fmaxf(v.z * rs, -448.f), 448.f);
    float q3 = fminf(fmaxf(v.w * rs, -448.f), 448.f);
    int p = __builtin_amdgcn_cvt_pk_fp8_f32(q0, q1, 0, false);  // bytes 0,1
    p     = __builtin_amdgcn_cvt_pk_fp8_f32(q2, q3, p, true);   // bytes 2,3
    return (uint32_t)p;
}

// ---------------------------------------------------------------------------
// Pass 1 (merged): quantize X (scaled) and convert W (exact) -> fp8 row-major.
// Validated rounds 8-18 (~31 us, at its HBM floor: 189 MB moved).
// ---------------------------------------------------------------------------
__global__ __launch_bounds__(256) void quant_xw_kernel(
    const float* __restrict__ x, const float* __restrict__ w,
    const float* __restrict__ s_ptr,
    uint32_t* __restrict__ xq, uint32_t* __restrict__ wq)
{
    if (blockIdx.x < 2048) {
        const float rs = 1.0f / s_ptr[0];
        const float4* xf4 = (const float4*)x;
        const int base = blockIdx.x * 4096 + threadIdx.x;
#pragma unroll
        for (int k = 0; k < 16; ++k) {
            const int i = base + k * 256;
            xq[i] = quant4(xf4[i], rs);
        }
    } else {
        const float4* wf4 = (const float4*)w;
        const int base = (blockIdx.x - 2048) * 1024 + threadIdx.x;
#pragma unroll
        for (int k = 0; k < 4; ++k) {
            const int i = base + k * 256;
            wq[i] = quant4(wf4[i], 1.0f);   // e4m3-representable: exact
        }
    }
}

// ---------------------------------------------------------------------------
// Pass 2: MX-fp8 GEMM, 256x256 tile, BK=128 — SINGLE-BUFFER LDS (64 KB)
// for 2 blocks/CU co-residency. This is r13's structure with the fatal
// launch-bounds artifact removed: r13's __launch_bounds__(512,4) produced
// VGPR_Count=64 (8-waves/SIMD cap) -> accumulator spill -> 1.1 GB scratch
// traffic. Here __launch_bounds__(512,2): cap >= 128 under either arg-2
// semantics, comfortably above the 108 VGPRs this body needs (r11 measured).
// Mechanism under test (m114): each block's exposed per-tile DMA drain at
// __syncthreads is covered by the co-resident block's MFMA phase.
// Staging/read swizzle math identical to r11 (validated, 3 reproductions).
// ---------------------------------------------------------------------------
#define G_BM 256
#define G_BN 256
#define G_NT 16                 // K / 128
#define G_GM (M_DIM / G_BM)     // 64
#define G_GN (N_DIM / G_BN)     // 8
#define SLOT 65536              // 32 KB A + 32 KB B (single buffer)

extern __shared__ uint8_t smem[];

__global__ __launch_bounds__(512, 2) void gemm_mx_sb2(
    const uint8_t* __restrict__ Aq,   // [M][K] fp8 row-major
    const uint8_t* __restrict__ Wq,   // [N][K] fp8 row-major
    const float* __restrict__ wscale,
    const float* __restrict__ iscale,
    float* __restrict__ out)
{
    const int tid  = threadIdx.x;
    const int lane = tid & 63;
    const int wid  = tid >> 6;

    // Bijective XCD swizzle (512 % 8 == 0); consecutive wg share bm.
    const int bid = blockIdx.x;
    const int wg  = (bid & 7) * (G_GM * G_GN / 8) + (bid >> 3);
    const int bm  = wg >> 3;
    const int bn  = wg & 7;
    const int rowBase = bm * G_BM;
    const int colBase = bn * G_BN;

    // Wave output: 128 rows x 64 cols.
    const int wrow = (wid >> 2) * 128;
    const int wcol = (wid & 3) * 64;

    const float scv = wscale[0] * iscale[0];

    // Staging (validated): thread t -> row 64i + (t>>3), global 16B pos
    // (t&7)^((t>>3)&7); LDS written linearly -> LDS(row,pos) = g(pos^(row&7)).
    const int sposx = (((lane & 7) ^ (lane >> 3)) * 16);
    const uint8_t* gA0 = Aq + (size_t)(rowBase + (tid >> 3)) * K_DIM + sposx;
    const uint8_t* gB0 = Wq + (size_t)(colBase + (tid >> 3)) * K_DIM + sposx;
    const int ldsW = wid * 1024;

    auto stage = [&](int tt) {
        const size_t koff = (size_t)tt * 128;
#pragma unroll
        for (int i = 0; i < 4; ++i)
            __builtin_amdgcn_global_load_lds(
                (const __attribute__((address_space(1))) void*)(gA0 + (size_t)i * (64 * K_DIM) + koff),
                (__attribute__((address_space(3))) void*)(smem + i * 8192 + ldsW),
                16, 0, 0);
#pragma unroll
        for (int i = 0; i < 4; ++i)
            __builtin_amdgcn_global_load_lds(
                (const __attribute__((address_space(1))) void*)(gB0 + (size_t)i * (64 * K_DIM) + koff),
                (__attribute__((address_space(3))) void*)(smem + 32768 + i * 8192 + ldsW),
                16, 0, 0);
    };

    // Fragment reads (validated): row fr=lane&15, k-block kb=lane>>4;
    // 32B block = LDS 16B-positions {2kb, 2kb^1} XOR (fr&7).
    const int fr  = lane & 15;
    const int pLo = (((lane >> 4) * 2) ^ (fr & 7)) * 16;

    f32x4 acc[8][4] = {};

    for (int t = 0; t < G_NT; ++t) {
        stage(t);
        __syncthreads();   // drains vmcnt(0): tile ready. Stall covered by the
                           // co-resident block's compute phase (the test).

        // B: all 4 n-frags live for the tile.
        i32x8 bv[4];
#pragma unroll
        for (int n = 0; n < 4; ++n) {
            const int ro = 32768 + (wcol + n * 16 + fr) * 128;
            u32x4 lo = *(const u32x4*)(smem + ro + pLo);
            u32x4 hi = *(const u32x4*)(smem + ro + (pLo ^ 16));
            bv[n] = (i32x8){(int)lo.x, (int)lo.y, (int)lo.z, (int)lo.w,
                            (int)hi.x, (int)hi.y, (int)hi.z, (int)hi.w};
        }
        // A: 8 m-frags just-in-time; compiler pipelines via fine lgkmcnt.
#pragma unroll
        for (int m = 0; m < 8; ++m) {
            const int ro = (wrow + m * 16 + fr) * 128;
            u32x4 lo = *(const u32x4*)(smem + ro + pLo);
            u32x4 hi = *(const u32x4*)(smem + ro + (pLo ^ 16));
            const i32x8 av = {(int)lo.x, (int)lo.y, (int)lo.z, (int)lo.w,
                              (int)hi.x, (int)hi.y, (int)hi.z, (int)hi.w};
#pragma unroll
            for (int n = 0; n < 4; ++n)
                acc[m][n] = __builtin_amdgcn_mfma_scale_f32_16x16x128_f8f6f4(
                    av, bv[n], acc[m][n], 0, 0, 0, SCALE_ONE, 0, SCALE_ONE);
        }
        __syncthreads();   // all waves done reading before next stage overwrites
    }

    // Epilogue. C/D layout: col = lane&15, row = (lane>>4)*4 + reg (validated).
    const int crow = (lane >> 4) << 2;
    const int ccol = lane & 15;
#pragma unroll
    for (int m = 0; m < 8; ++m) {
#pragma unroll
        for (int n = 0; n < 4; ++n) {
            const size_t base = (size_t)(rowBase + wrow + m * 16 + crow) * N_DIM
                              + (colBase + wcol + n * 16 + ccol);
#pragma unroll
            for (int r = 0; r < 4; ++r)
                out[base + (size_t)r * N_DIM] = acc[m][n][r] * scv;
        }
    }
}

// ---------------------------------------------------------------------------
// Fallback (attribute failure / ws too small): proven round-4 fused kernel.
// ---------------------------------------------------------------------------
__global__ __launch_bounds__(256) void fused_fp8_gemm(
    const float* __restrict__ X, const float* __restrict__ Wf,
    const float* __restrict__ wscale, const float* __restrict__ iscale,
    float* __restrict__ out)
{
    __shared__ uint8_t smA[2][128 * 64];
    __shared__ uint8_t smB[2][128 * 64];

    const int tid  = threadIdx.x;
    const int lane = tid & 63;
    const int wid  = tid >> 6;

    const float s  = iscale[0];
    const float rs = 1.0f / s;
    const float sc = wscale[0] * s;

    const int bid = blockIdx.x;
    const int wg  = (bid & 7) * 256 + (bid >> 3);
    const int bm  = wg >> 4;
    const int bn  = wg & 15;
    const int rowBase = bm * 128;
    const int colBase = bn * 128;
    const int wrow = (wid >> 1) * 64;
    const int wcol = (wid & 1) * 64;
    const int ar = tid >> 1;
    const int ah = (tid & 1) * 32;

    const float* Xrow = X  + (size_t)(rowBase + ar) * K_DIM;
    const float* Wrow = Wf + (size_t)(colBase + ar) * K_DIM;

    float4 areg[8], breg[8];
    auto load_tile = [&](int kt) {
        const int k0 = kt * 64;
#pragma unroll
        for (int j = 0; j < 8; ++j) areg[j] = *(const float4*)(Xrow + k0 + ah + j * 4);
#pragma unroll
        for (int j = 0; j < 8; ++j) breg[j] = *(const float4*)(Wrow + k0 + ah + j * 4);
    };
    auto write_tile = [&](int buf) {
        uint32_t aq[8], bq[8];
#pragma unroll
        for (int j = 0; j < 8; ++j) { aq[j] = quant4(areg[j], rs); bq[j] = quant4(breg[j], 1.0f); }
        *(u32x4*)&smA[buf][ar * 64 + ah]      = *(const u32x4*)&aq[0];
        *(u32x4*)&smA[buf][ar * 64 + ah + 16] = *(const u32x4*)&aq[4];
        *(u32x4*)&smB[buf][ar * 64 + ah]      = *(const u32x4*)&bq[0];
        *(u32x4*)&smB[buf][ar * 64 + ah + 16] = *(const u32x4*)&bq[4];
    };

    f32x4 acc[4][4] = {};
    load_tile(0); write_tile(0); __syncthreads();
    for (int kt = 0; kt < 32; ++kt) {
        const int cur = kt & 1;
        if (kt + 1 < 32) load_tile(kt + 1);
        const uint8_t* pA = smA[cur];
        const uint8_t* pB = smB[cur];
        const int afr = lane & 15, koff = (lane >> 4) << 3;
#pragma unroll
        for (int kk = 0; kk < 2; ++kk) {
            long long a[4], b[4];
#pragma unroll
            for (int m = 0; m < 4; ++m)
                a[m] = *(const long long*)(pA + (wrow + m * 16 + afr) * 64 + kk * 32 + koff);
#pragma unroll
            for (int n = 0; n < 4; ++n)
                b[n] = *(const long long*)(pB + (wcol + n * 16 + afr) * 64 + kk * 32 + koff);
#pragma unroll
            for (int m = 0; m < 4; ++m)
#pragma unroll
                for (int n = 0; n < 4; ++n)
                    acc[m][n] = __builtin_amdgcn_mfma_f32_16x16x32_fp8_fp8(
                        a[m], b[n], acc[m][n], 0, 0, 0);
        }
        if (kt + 1 < 32) write_tile(cur ^ 1);
        __syncthreads();
    }
    const int crow = (lane >> 4) << 2, ccol = lane & 15;
#pragma unroll
    for (int m = 0; m < 4; ++m)
#pragma unroll
        for (int n = 0; n < 4; ++n) {
            const size_t base = (size_t)(rowBase + wrow + m * 16 + crow) * N_DIM
                              + (colBase + wcol + n * 16 + ccol);
#pragma unroll
            for (int r = 0; r < 4; ++r)
                out[base + (size_t)r * N_DIM] = acc[m][n][r] * sc;
        }
}

extern "C" void kernel_launch(void* const* d_in, const int* in_sizes, int n_in,
                              void* d_out, int out_size, void* d_ws, size_t ws_size,
                              hipStream_t stream) {
    const float* x      = (const float*)d_in[0];
    const float* w      = (const float*)d_in[1];   // fp8 values stored as f32
    const float* wscale = (const float*)d_in[2];
    const float* iscale = (const float*)d_in[3];
    float*       out    = (float*)d_out;

    const size_t needA = (size_t)M_DIM * K_DIM;    // 33.5 MB fp8 X
    const size_t needW = (size_t)N_DIM * K_DIM;    //  4.2 MB fp8 W

    hipError_t e = hipFuncSetAttribute((const void*)gemm_mx_sb2,
                                       hipFuncAttributeMaxDynamicSharedMemorySize,
                                       SLOT);

    if (e == hipSuccess && ws_size >= needA + needW) {
        uint32_t* xq = (uint32_t*)d_ws;
        uint32_t* wq = (uint32_t*)((uint8_t*)d_ws + needA);
        quant_xw_kernel<<<3072, 256, 0, stream>>>(x, w, iscale, xq, wq);
        gemm_mx_sb2<<<G_GM * G_GN, 512, SLOT, stream>>>(
            (const uint8_t*)xq, (const uint8_t*)wq, wscale, iscale, out);
    } else {
        fused_fp8_gemm<<<2048, 256, 0, stream>>>(x, w, wscale, iscale, out);
    }
}

// Round 20
// 111.658 us; speedup vs baseline: 1.1274x; 1.1274x over previous
//
#include <hip/hip_runtime.h>
#include <hip/hip_bf16.h>
#include <stdint.h>

// x[2,8192,2048] f32; weight[2048,2048] fp8e4m3fn pushed as f32 values;
// scales pushed as f32 scalars (established rounds 0-19). out[2,8192,2048] f32.
// FINAL: ROUND-11 KERNEL VERBATIM — best measured config, reproduced 3x
// (r11=112.0, r16=111.4, r18=111.5 us total; GEMM 79.6-80.8 us ~ 1720 TF).
// 256x256 tile, BK=128, dbuf-2, single-barrier compiler-scheduled loop,
// global_load_lds w=16, XOR-16B-pos swizzle (pre-swizzled global src),
// MX-fp8 mfma_scale 16x16x128 with unit e8m0 scales, XCD-bijective swizzle.
// Structural survey r8/r9/r12/r13/r14/r15/r17/r19: every variant regressed —
// plain-HIP 2-barrier ceiling (~35% MfmaUtil) per m97/m232 documentation;
// the path beyond needs the co-designed asm 8-phase stack (3 attempts failed
// reproduction, consistent with m152).
#define M_DIM 16384
#define N_DIM 2048
#define K_DIM 2048

typedef float    f32x4 __attribute__((ext_vector_type(4)));
typedef uint32_t u32x4 __attribute__((ext_vector_type(4)));
typedef int      i32x8 __attribute__((ext_vector_type(8)));

#define SCALE_ONE 0x7F7F7F7F   // e8m0 exp 127 -> 1.0 in all byte lanes

__device__ inline uint32_t quant4(float4 v, float rs) {
    float q0 = fminf(fmaxf(v.x * rs, -448.f), 448.f);
    float q1 = fminf(fmaxf(v.y * rs, -448.f), 448.f);
    float q2 = fminf(fmaxf(v.z * rs, -448.f), 448.f);
    float q3 = fminf(fmaxf(v.w * rs, -448.f), 448.f);
    int p = __builtin_amdgcn_cvt_pk_fp8_f32(q0, q1, 0, false);  // bytes 0,1
    p     = __builtin_amdgcn_cvt_pk_fp8_f32(q2, q3, p, true);   // bytes 2,3
    return (uint32_t)p;
}

// ---------------------------------------------------------------------------
// Pass 1 (merged): quantize X (scaled) and convert W (exact) -> fp8 row-major.
// Validated rounds 8-19 (~31 us, at its HBM floor: 189 MB moved).
// ---------------------------------------------------------------------------
__global__ __launch_bounds__(256) void quant_xw_kernel(
    const float* __restrict__ x, const float* __restrict__ w,
    const float* __restrict__ s_ptr,
    uint32_t* __restrict__ xq, uint32_t* __restrict__ wq)
{
    if (blockIdx.x < 2048) {
        const float rs = 1.0f / s_ptr[0];
        const float4* xf4 = (const float4*)x;
        const int base = blockIdx.x * 4096 + threadIdx.x;
#pragma unroll
        for (int k = 0; k < 16; ++k) {
            const int i = base + k * 256;
            xq[i] = quant4(xf4[i], rs);
        }
    } else {
        const float4* wf4 = (const float4*)w;
        const int base = (blockIdx.x - 2048) * 1024 + threadIdx.x;
#pragma unroll
        for (int k = 0; k < 4; ++k) {
            const int i = base + k * 256;
            wq[i] = quant4(wf4[i], 1.0f);   // e4m3-representable: exact
        }
    }
}

// ---------------------------------------------------------------------------
// Pass 2: MX-fp8 GEMM (round-11 verbatim).
// ---------------------------------------------------------------------------
#define G_BM 256
#define G_BN 256
#define G_NT 16                 // K / 128
#define G_GM (M_DIM / G_BM)     // 64
#define G_GN (N_DIM / G_BN)     // 8
#define SLOT 65536              // 32 KB A + 32 KB B

extern __shared__ uint8_t smem[];

__global__ __launch_bounds__(512, 1) void gemm_mx_256sq(
    const uint8_t* __restrict__ Aq,   // [M][K] fp8 row-major
    const uint8_t* __restrict__ Wq,   // [N][K] fp8 row-major
    const float* __restrict__ wscale,
    const float* __restrict__ iscale,
    float* __restrict__ out)
{
    const int tid  = threadIdx.x;
    const int lane = tid & 63;
    const int wid  = tid >> 6;

    // Bijective XCD swizzle (512 % 8 == 0); consecutive wg share bm -> the
    // 512 KB A panel and whole 4 MB Wq stay L2-warm per XCD.
    const int bid = blockIdx.x;
    const int wg  = (bid & 7) * (G_GM * G_GN / 8) + (bid >> 3);
    const int bm  = wg >> 3;
    const int bn  = wg & 7;
    const int rowBase = bm * G_BM;
    const int colBase = bn * G_BN;

    // Wave output: 128 rows x 64 cols.
    const int wrow = (wid >> 2) * 128;   // wm in {0,1}
    const int wcol = (wid & 3) * 64;     // wn in {0..3}

    const float scv = wscale[0] * iscale[0];

    // Staging: 8 issues/thread/tile, issue i covers 64 rows (i<4: A, else B).
    // Thread t -> row 64i + (t>>3), global pos16 (t&7)^((t>>3)&7) (pre-swizzle;
    // row&7 == (t>>3)&7 since 64i and 8*wid are multiples of 8).
    const int sposx = (((lane & 7) ^ (lane >> 3)) * 16);
    const uint8_t* gA0 = Aq + (size_t)(rowBase + (tid >> 3)) * K_DIM + sposx;
    const uint8_t* gB0 = Wq + (size_t)(colBase + (tid >> 3)) * K_DIM + sposx;
    const int ldsW = wid * 1024;   // wave's 8-row band within each 64-row region

    auto stage = [&](int buf, int tt) {
        const size_t koff = (size_t)tt * 128;
        uint8_t* sb = smem + buf * SLOT;
#pragma unroll
        for (int i = 0; i < 4; ++i)
            __builtin_amdgcn_global_load_lds(
                (const __attribute__((address_space(1))) void*)(gA0 + (size_t)i * (64 * K_DIM) + koff),
                (__attribute__((address_space(3))) void*)(sb + i * 8192 + ldsW),
                16, 0, 0);
#pragma unroll
        for (int i = 0; i < 4; ++i)
            __builtin_amdgcn_global_load_lds(
                (const __attribute__((address_space(1))) void*)(gB0 + (size_t)i * (64 * K_DIM) + koff),
                (__attribute__((address_space(3))) void*)(sb + 32768 + i * 8192 + ldsW),
                16, 0, 0);
    };

    // Fragment reads: lane holds row fr=lane&15 of each frag, k-block
    // kb=lane>>4 (32 B = 16B-positions {2kb, 2kb^1} XOR (fr&7)).
    const int fr  = lane & 15;
    const int rx  = fr & 7;
    const int pLo = (((lane >> 4) * 2) ^ rx) * 16;

    f32x4 acc[8][4] = {};

    stage(0, 0);
    __syncthreads();   // compiler drains vmcnt(0): tile 0 resident

    for (int t = 0; t < G_NT; ++t) {
        const int cur = t & 1;
        if (t + 1 < G_NT) stage(cur ^ 1, t + 1);   // DMA prefetch, issued first

        const uint8_t* sb = smem + cur * SLOT;

        // B: all 4 n-frags live for the whole tile (32 VGPR).
        i32x8 bv[4];
#pragma unroll
        for (int n = 0; n < 4; ++n) {
            const int ro = 32768 + (wcol + n * 16 + fr) * 128;
            u32x4 lo = *(const u32x4*)(sb + ro + pLo);
            u32x4 hi = *(const u32x4*)(sb + ro + (pLo ^ 16));
            bv[n] = (i32x8){(int)lo.x, (int)lo.y, (int)lo.z, (int)lo.w,
                            (int)hi.x, (int)hi.y, (int)hi.z, (int)hi.w};
        }
        // A: 8 m-frags, read just-in-time per m; compiler pipelines reads
        // against the previous m's MFMAs via fine lgkmcnt (proven behavior).
#pragma unroll
        for (int m = 0; m < 8; ++m) {
            const int ro = (wrow + m * 16 + fr) * 128;
            u32x4 lo = *(const u32x4*)(sb + ro + pLo);
            u32x4 hi = *(const u32x4*)(sb + ro + (pLo ^ 16));
            const i32x8 av = {(int)lo.x, (int)lo.y, (int)lo.z, (int)lo.w,
                              (int)hi.x, (int)hi.y, (int)hi.z, (int)hi.w};
#pragma unroll
            for (int n = 0; n < 4; ++n)
                acc[m][n] = __builtin_amdgcn_mfma_scale_f32_16x16x128_f8f6f4(
                    av, bv[n], acc[m][n], 0, 0, 0, SCALE_ONE, 0, SCALE_ONE);
        }
        __syncthreads();   // joins waves + drains prefetch before buffer swap
    }

    // Epilogue. C/D layout: col = lane&15, row = (lane>>4)*4 + reg (validated).
    const int crow = (lane >> 4) << 2;
    const int ccol = lane & 15;
#pragma unroll
    for (int m = 0; m < 8; ++m) {
#pragma unroll
        for (int n = 0; n < 4; ++n) {
            const size_t base = (size_t)(rowBase + wrow + m * 16 + crow) * N_DIM
                              + (colBase + wcol + n * 16 + ccol);
#pragma unroll
            for (int r = 0; r < 4; ++r)
                out[base + (size_t)r * N_DIM] = acc[m][n][r] * scv;
        }
    }
}

// ---------------------------------------------------------------------------
// Fallback (attribute failure / ws too small): proven round-4 fused kernel.
// ---------------------------------------------------------------------------
__global__ __launch_bounds__(256) void fused_fp8_gemm(
    const float* __restrict__ X, const float* __restrict__ Wf,
    const float* __restrict__ wscale, const float* __restrict__ iscale,
    float* __restrict__ out)
{
    __shared__ uint8_t smA[2][128 * 64];
    __shared__ uint8_t smB[2][128 * 64];

    const int tid  = threadIdx.x;
    const int lane = tid & 63;
    const int wid  = tid >> 6;

    const float s  = iscale[0];
    const float rs = 1.0f / s;
    const float sc = wscale[0] * s;

    const int bid = blockIdx.x;
    const int wg  = (bid & 7) * 256 + (bid >> 3);
    const int bm  = wg >> 4;
    const int bn  = wg & 15;
    const int rowBase = bm * 128;
    const int colBase = bn * 128;
    const int wrow = (wid >> 1) * 64;
    const int wcol = (wid & 1) * 64;
    const int ar = tid >> 1;
    const int ah = (tid & 1) * 32;

    const float* Xrow = X  + (size_t)(rowBase + ar) * K_DIM;
    const float* Wrow = Wf + (size_t)(colBase + ar) * K_DIM;

    float4 areg[8], breg[8];
    auto load_tile = [&](int kt) {
        const int k0 = kt * 64;
#pragma unroll
        for (int j = 0; j < 8; ++j) areg[j] = *(const float4*)(Xrow + k0 + ah + j * 4);
#pragma unroll
        for (int j = 0; j < 8; ++j) breg[j] = *(const float4*)(Wrow + k0 + ah + j * 4);
    };
    auto write_tile = [&](int buf) {
        uint32_t aq[8], bq[8];
#pragma unroll
        for (int j = 0; j < 8; ++j) { aq[j] = quant4(areg[j], rs); bq[j] = quant4(breg[j], 1.0f); }
        *(u32x4*)&smA[buf][ar * 64 + ah]      = *(const u32x4*)&aq[0];
        *(u32x4*)&smA[buf][ar * 64 + ah + 16] = *(const u32x4*)&aq[4];
        *(u32x4*)&smB[buf][ar * 64 + ah]      = *(const u32x4*)&bq[0];
        *(u32x4*)&smB[buf][ar * 64 + ah + 16] = *(const u32x4*)&bq[4];
    };

    f32x4 acc[4][4] = {};
    load_tile(0); write_tile(0); __syncthreads();
    for (int kt = 0; kt < 32; ++kt) {
        const int cur = kt & 1;
        if (kt + 1 < 32) load_tile(kt + 1);
        const uint8_t* pA = smA[cur];
        const uint8_t* pB = smB[cur];
        const int afr = lane & 15, koff = (lane >> 4) << 3;
#pragma unroll
        for (int kk = 0; kk < 2; ++kk) {
            long long a[4], b[4];
#pragma unroll
            for (int m = 0; m < 4; ++m)
                a[m] = *(const long long*)(pA + (wrow + m * 16 + afr) * 64 + kk * 32 + koff);
#pragma unroll
            for (int n = 0; n < 4; ++n)
                b[n] = *(const long long*)(pB + (wcol + n * 16 + afr) * 64 + kk * 32 + koff);
#pragma unroll
            for (int m = 0; m < 4; ++m)
#pragma unroll
                for (int n = 0; n < 4; ++n)
                    acc[m][n] = __builtin_amdgcn_mfma_f32_16x16x32_fp8_fp8(
                        a[m], b[n], acc[m][n], 0, 0, 0);
        }
        if (kt + 1 < 32) write_tile(cur ^ 1);
        __syncthreads();
    }
    const int crow = (lane >> 4) << 2, ccol = lane & 15;
#pragma unroll
    for (int m = 0; m < 4; ++m)
#pragma unroll
        for (int n = 0; n < 4; ++n) {
            const size_t base = (size_t)(rowBase + wrow + m * 16 + crow) * N_DIM
                              + (colBase + wcol + n * 16 + ccol);
#pragma unroll
            for (int r = 0; r < 4; ++r)
                out[base + (size_t)r * N_DIM] = acc[m][n][r] * sc;
        }
}

extern "C" void kernel_launch(void* const* d_in, const int* in_sizes, int n_in,
                              void* d_out, int out_size, void* d_ws, size_t ws_size,
                              hipStream_t stream) {
    const float* x      = (const float*)d_in[0];
    const float* w      = (const float*)d_in[1];   // fp8 values stored as f32
    const float* wscale = (const float*)d_in[2];
    const float* iscale = (const float*)d_in[3];
    float*       out    = (float*)d_out;

    const size_t needA = (size_t)M_DIM * K_DIM;    // 33.5 MB fp8 X
    const size_t needW = (size_t)N_DIM * K_DIM;    //  4.2 MB fp8 W

    hipError_t e = hipFuncSetAttribute((const void*)gemm_mx_256sq,
                                       hipFuncAttributeMaxDynamicSharedMemorySize,
                                       2 * SLOT);

    if (e == hipSuccess && ws_size >= needA + needW) {
        uint32_t* xq = (uint32_t*)d_ws;
        uint32_t* wq = (uint32_t*)((uint8_t*)d_ws + needA);
        quant_xw_kernel<<<3072, 256, 0, stream>>>(x, w, iscale, xq, wq);
        gemm_mx_256sq<<<G_GM * G_GN, 512, 2 * SLOT, stream>>>(
            (const uint8_t*)xq, (const uint8_t*)wq, wscale, iscale, out);
    } else {
        fused_fp8_gemm<<<2048, 256, 0, stream>>>(x, w, wscale, iscale, out);
    }
}

// Round 21
// 111.231 us; speedup vs baseline: 1.1317x; 1.0038x over previous
//
#include <hip/hip_runtime.h>
#include <hip/hip_bf16.h>
#include <stdint.h>

// x[2,8192,2048] f32; weight[2048,2048] fp8e4m3fn pushed as f32 values;
// scales pushed as f32 scalars (established rounds 0-20). out[2,8192,2048] f32.
// FINAL: best measured config, reproduced 4x (112.0/111.4/111.5/111.7 us
// total; GEMM 79.2-81.0 us ~ 1720 TF effective on the MX pipe).
// 256x256 tile, BK=128, dbuf-2, single-barrier compiler-scheduled loop,
// global_load_lds w=16, XOR-16B-pos swizzle (pre-swizzled global src),
// MX-fp8 mfma_scale 16x16x128 with unit e8m0 scales, XCD-bijective swizzle.
// Structural ceiling statement: counted-vmcnt deep-pipeline (the documented
// +38-73% lever) needs a >=3-deep LDS ring = 3 x 64 KB = 192 KB > 160 KB/CU
// at this geometry; at geometries where it fits (256x128) the extra LDS
// reads/FLOP cost more than the pipeline gains (measured 106 us). Eight
// structural variants (r8,r9,r12,r13,r14,r15,r17,r19) all regressed vs this.
#define M_DIM 16384
#define N_DIM 2048
#define K_DIM 2048

typedef float    f32x4 __attribute__((ext_vector_type(4)));
typedef uint32_t u32x4 __attribute__((ext_vector_type(4)));
typedef int      i32x8 __attribute__((ext_vector_type(8)));

#define SCALE_ONE 0x7F7F7F7F   // e8m0 exp 127 -> 1.0 in all byte lanes

__device__ inline uint32_t quant4(float4 v, float rs) {
    float q0 = fminf(fmaxf(v.x * rs, -448.f), 448.f);
    float q1 = fminf(fmaxf(v.y * rs, -448.f), 448.f);
    float q2 = fminf(fmaxf(v.z * rs, -448.f), 448.f);
    float q3 = fminf(fmaxf(v.w * rs, -448.f), 448.f);
    int p = __builtin_amdgcn_cvt_pk_fp8_f32(q0, q1, 0, false);  // bytes 0,1
    p     = __builtin_amdgcn_cvt_pk_fp8_f32(q2, q3, p, true);   // bytes 2,3
    return (uint32_t)p;
}

// ---------------------------------------------------------------------------
// Pass 1 (merged): quantize X (scaled) and convert W (exact) -> fp8 row-major.
// Validated rounds 8-20 (~31 us, at its HBM floor: 189 MB moved).
// ---------------------------------------------------------------------------
__global__ __launch_bounds__(256) void quant_xw_kernel(
    const float* __restrict__ x, const float* __restrict__ w,
    const float* __restrict__ s_ptr,
    uint32_t* __restrict__ xq, uint32_t* __restrict__ wq)
{
    if (blockIdx.x < 2048) {
        const float rs = 1.0f / s_ptr[0];
        const float4* xf4 = (const float4*)x;
        const int base = blockIdx.x * 4096 + threadIdx.x;
#pragma unroll
        for (int k = 0; k < 16; ++k) {
            const int i = base + k * 256;
            xq[i] = quant4(xf4[i], rs);
        }
    } else {
        const float4* wf4 = (const float4*)w;
        const int base = (blockIdx.x - 2048) * 1024 + threadIdx.x;
#pragma unroll
        for (int k = 0; k < 4; ++k) {
            const int i = base + k * 256;
            wq[i] = quant4(wf4[i], 1.0f);   // e4m3-representable: exact
        }
    }
}

// ---------------------------------------------------------------------------
// Pass 2: MX-fp8 GEMM (round-11 verbatim, 4x-reproduced best).
// ---------------------------------------------------------------------------
#define G_BM 256
#define G_BN 256
#define G_NT 16                 // K / 128
#define G_GM (M_DIM / G_BM)     // 64
#define G_GN (N_DIM / G_BN)     // 8
#define SLOT 65536              // 32 KB A + 32 KB B

extern __shared__ uint8_t smem[];

__global__ __launch_bounds__(512, 1) void gemm_mx_256sq(
    const uint8_t* __restrict__ Aq,   // [M][K] fp8 row-major
    const uint8_t* __restrict__ Wq,   // [N][K] fp8 row-major
    const float* __restrict__ wscale,
    const float* __restrict__ iscale,
    float* __restrict__ out)
{
    const int tid  = threadIdx.x;
    const int lane = tid & 63;
    const int wid  = tid >> 6;

    // Bijective XCD swizzle (512 % 8 == 0); consecutive wg share bm -> the
    // 512 KB A panel and whole 4 MB Wq stay L2-warm per XCD.
    const int bid = blockIdx.x;
    const int wg  = (bid & 7) * (G_GM * G_GN / 8) + (bid >> 3);
    const int bm  = wg >> 3;
    const int bn  = wg & 7;
    const int rowBase = bm * G_BM;
    const int colBase = bn * G_BN;

    // Wave output: 128 rows x 64 cols.
    const int wrow = (wid >> 2) * 128;   // wm in {0,1}
    const int wcol = (wid & 3) * 64;     // wn in {0..3}

    const float scv = wscale[0] * iscale[0];

    // Staging: 8 issues/thread/tile, issue i covers 64 rows (i<4: A, else B).
    // Thread t -> row 64i + (t>>3), global pos16 (t&7)^((t>>3)&7) (pre-swizzle;
    // row&7 == (t>>3)&7 since 64i and 8*wid are multiples of 8).
    const int sposx = (((lane & 7) ^ (lane >> 3)) * 16);
    const uint8_t* gA0 = Aq + (size_t)(rowBase + (tid >> 3)) * K_DIM + sposx;
    const uint8_t* gB0 = Wq + (size_t)(colBase + (tid >> 3)) * K_DIM + sposx;
    const int ldsW = wid * 1024;   // wave's 8-row band within each 64-row region

    auto stage = [&](int buf, int tt) {
        const size_t koff = (size_t)tt * 128;
        uint8_t* sb = smem + buf * SLOT;
#pragma unroll
        for (int i = 0; i < 4; ++i)
            __builtin_amdgcn_global_load_lds(
                (const __attribute__((address_space(1))) void*)(gA0 + (size_t)i * (64 * K_DIM) + koff),
                (__attribute__((address_space(3))) void*)(sb + i * 8192 + ldsW),
                16, 0, 0);
#pragma unroll
        for (int i = 0; i < 4; ++i)
            __builtin_amdgcn_global_load_lds(
                (const __attribute__((address_space(1))) void*)(gB0 + (size_t)i * (64 * K_DIM) + koff),
                (__attribute__((address_space(3))) void*)(sb + 32768 + i * 8192 + ldsW),
                16, 0, 0);
    };

    // Fragment reads: lane holds row fr=lane&15 of each frag, k-block
    // kb=lane>>4 (32 B = 16B-positions {2kb, 2kb^1} XOR (fr&7)).
    const int fr  = lane & 15;
    const int rx  = fr & 7;
    const int pLo = (((lane >> 4) * 2) ^ rx) * 16;

    f32x4 acc[8][4] = {};

    stage(0, 0);
    __syncthreads();   // compiler drains vmcnt(0): tile 0 resident

    for (int t = 0; t < G_NT; ++t) {
        const int cur = t & 1;
        if (t + 1 < G_NT) stage(cur ^ 1, t + 1);   // DMA prefetch, issued first

        const uint8_t* sb = smem + cur * SLOT;

        // B: all 4 n-frags live for the whole tile (32 VGPR).
        i32x8 bv[4];
#pragma unroll
        for (int n = 0; n < 4; ++n) {
            const int ro = 32768 + (wcol + n * 16 + fr) * 128;
            u32x4 lo = *(const u32x4*)(sb + ro + pLo);
            u32x4 hi = *(const u32x4*)(sb + ro + (pLo ^ 16));
            bv[n] = (i32x8){(int)lo.x, (int)lo.y, (int)lo.z, (int)lo.w,
                            (int)hi.x, (int)hi.y, (int)hi.z, (int)hi.w};
        }
        // A: 8 m-frags, read just-in-time per m; compiler pipelines reads
        // against the previous m's MFMAs via fine lgkmcnt (proven behavior).
#pragma unroll
        for (int m = 0; m < 8; ++m) {
            const int ro = (wrow + m * 16 + fr) * 128;
            u32x4 lo = *(const u32x4*)(sb + ro + pLo);
            u32x4 hi = *(const u32x4*)(sb + ro + (pLo ^ 16));
            const i32x8 av = {(int)lo.x, (int)lo.y, (int)lo.z, (int)lo.w,
                              (int)hi.x, (int)hi.y, (int)hi.z, (int)hi.w};
#pragma unroll
            for (int n = 0; n < 4; ++n)
                acc[m][n] = __builtin_amdgcn_mfma_scale_f32_16x16x128_f8f6f4(
                    av, bv[n], acc[m][n], 0, 0, 0, SCALE_ONE, 0, SCALE_ONE);
        }
        __syncthreads();   // joins waves + drains prefetch before buffer swap
    }

    // Epilogue. C/D layout: col = lane&15, row = (lane>>4)*4 + reg (validated).
    const int crow = (lane >> 4) << 2;
    const int ccol = lane & 15;
#pragma unroll
    for (int m = 0; m < 8; ++m) {
#pragma unroll
        for (int n = 0; n < 4; ++n) {
            const size_t base = (size_t)(rowBase + wrow + m * 16 + crow) * N_DIM
                              + (colBase + wcol + n * 16 + ccol);
#pragma unroll
            for (int r = 0; r < 4; ++r)
                out[base + (size_t)r * N_DIM] = acc[m][n][r] * scv;
        }
    }
}

// ---------------------------------------------------------------------------
// Fallback (attribute failure / ws too small): proven round-4 fused kernel.
// ---------------------------------------------------------------------------
__global__ __launch_bounds__(256) void fused_fp8_gemm(
    const float* __restrict__ X, const float* __restrict__ Wf,
    const float* __restrict__ wscale, const float* __restrict__ iscale,
    float* __restrict__ out)
{
    __shared__ uint8_t smA[2][128 * 64];
    __shared__ uint8_t smB[2][128 * 64];

    const int tid  = threadIdx.x;
    const int lane = tid & 63;
    const int wid  = tid >> 6;

    const float s  = iscale[0];
    const float rs = 1.0f / s;
    const float sc = wscale[0] * s;

    const int bid = blockIdx.x;
    const int wg  = (bid & 7) * 256 + (bid >> 3);
    const int bm  = wg >> 4;
    const int bn  = wg & 15;
    const int rowBase = bm * 128;
    const int colBase = bn * 128;
    const int wrow = (wid >> 1) * 64;
    const int wcol = (wid & 1) * 64;
    const int ar = tid >> 1;
    const int ah = (tid & 1) * 32;

    const float* Xrow = X  + (size_t)(rowBase + ar) * K_DIM;
    const float* Wrow = Wf + (size_t)(colBase + ar) * K_DIM;

    float4 areg[8], breg[8];
    auto load_tile = [&](int kt) {
        const int k0 = kt * 64;
#pragma unroll
        for (int j = 0; j < 8; ++j) areg[j] = *(const float4*)(Xrow + k0 + ah + j * 4);
#pragma unroll
        for (int j = 0; j < 8; ++j) breg[j] = *(const float4*)(Wrow + k0 + ah + j * 4);
    };
    auto write_tile = [&](int buf) {
        uint32_t aq[8], bq[8];
#pragma unroll
        for (int j = 0; j < 8; ++j) { aq[j] = quant4(areg[j], rs); bq[j] = quant4(breg[j], 1.0f); }
        *(u32x4*)&smA[buf][ar * 64 + ah]      = *(const u32x4*)&aq[0];
        *(u32x4*)&smA[buf][ar * 64 + ah + 16] = *(const u32x4*)&aq[4];
        *(u32x4*)&smB[buf][ar * 64 + ah]      = *(const u32x4*)&bq[0];
        *(u32x4*)&smB[buf][ar * 64 + ah + 16] = *(const u32x4*)&bq[4];
    };

    f32x4 acc[4][4] = {};
    load_tile(0); write_tile(0); __syncthreads();
    for (int kt = 0; kt < 32; ++kt) {
        const int cur = kt & 1;
        if (kt + 1 < 32) load_tile(kt + 1);
        const uint8_t* pA = smA[cur];
        const uint8_t* pB = smB[cur];
        const int afr = lane & 15, koff = (lane >> 4) << 3;
#pragma unroll
        for (int kk = 0; kk < 2; ++kk) {
            long long a[4], b[4];
#pragma unroll
            for (int m = 0; m < 4; ++m)
                a[m] = *(const long long*)(pA + (wrow + m * 16 + afr) * 64 + kk * 32 + koff);
#pragma unroll
            for (int n = 0; n < 4; ++n)
                b[n] = *(const long long*)(pB + (wcol + n * 16 + afr) * 64 + kk * 32 + koff);
#pragma unroll
            for (int m = 0; m < 4; ++m)
#pragma unroll
                for (int n = 0; n < 4; ++n)
                    acc[m][n] = __builtin_amdgcn_mfma_f32_16x16x32_fp8_fp8(
                        a[m], b[n], acc[m][n], 0, 0, 0);
        }
        if (kt + 1 < 32) write_tile(cur ^ 1);
        __syncthreads();
    }
    const int crow = (lane >> 4) << 2, ccol = lane & 15;
#pragma unroll
    for (int m = 0; m < 4; ++m)
#pragma unroll
        for (int n = 0; n < 4; ++n) {
            const size_t base = (size_t)(rowBase + wrow + m * 16 + crow) * N_DIM
                              + (colBase + wcol + n * 16 + ccol);
#pragma unroll
            for (int r = 0; r < 4; ++r)
                out[base + (size_t)r * N_DIM] = acc[m][n][r] * sc;
        }
}

extern "C" void kernel_launch(void* const* d_in, const int* in_sizes, int n_in,
                              void* d_out, int out_size, void* d_ws, size_t ws_size,
                              hipStream_t stream) {
    const float* x      = (const float*)d_in[0];
    const float* w      = (const float*)d_in[1];   // fp8 values stored as f32
    const float* wscale = (const float*)d_in[2];
    const float* iscale = (const float*)d_in[3];
    float*       out    = (float*)d_out;

    const size_t needA = (size_t)M_DIM * K_DIM;    // 33.5 MB fp8 X
    const size_t needW = (size_t)N_DIM * K_DIM;    //  4.2 MB fp8 W

    hipError_t e = hipFuncSetAttribute((const void*)gemm_mx_256sq,
                                       hipFuncAttributeMaxDynamicSharedMemorySize,
                                       2 * SLOT);

    if (e == hipSuccess && ws_size >= needA + needW) {
        uint32_t* xq = (uint32_t*)d_ws;
        uint32_t* wq = (uint32_t*)((uint8_t*)d_ws + needA);
        quant_xw_kernel<<<3072, 256, 0, stream>>>(x, w, iscale, xq, wq);
        gemm_mx_256sq<<<G_GM * G_GN, 512, 2 * SLOT, stream>>>(
            (const uint8_t*)xq, (const uint8_t*)wq, wscale, iscale, out);
    } else {
        fused_fp8_gemm<<<2048, 256, 0, stream>>>(x, w, wscale, iscale, out);
    }
}